// Round 3
// baseline (5662.477 us; speedup 1.0000x reference)
//
#include <hip/hip_runtime.h>
#include <hip/hip_bf16.h>

// ---- problem geometry ----
#define NROWS   131072          // 32*4096
#define DIM     64
#define NEMB    512
// output offsets (floats)
#define OUT_Q     0
#define OUT_DIFF  8388608
#define OUT_IND   8388609
#define OUT_OH    8519681      // 8388609 + 131072
#define OUT_ES    8520193      // OUT_OH + 512
// ws layout (floats)
#define WS_ET     512          // embedT [512][64]
#define WS_PART   33280        // 512 + 32768

__global__ __launch_bounds__(256) void vq_prep(const float* __restrict__ embed,
                                               float* __restrict__ ws,
                                               float* __restrict__ out, int P) {
  const int tid = blockIdx.x * 256 + threadIdx.x;
  const int nth = gridDim.x * 256;
  // embedT[j][d] = embed[d][j]   (for the coalesced quantize gather)
  for (int e = tid; e < NEMB * DIM; e += nth) {
    int j = e >> 6, d = e & 63;
    ws[WS_ET + e] = embed[d * NEMB + j];
  }
  // zero accumulator output regions (diff, onehot, embed_sum)
  if (tid == 0) out[OUT_DIFF] = 0.f;
  for (int e = tid; e < NEMB + NEMB * DIM; e += nth) out[OUT_OH + e] = 0.f;
  // zero ws partials
  for (long e = tid; e < (long)P * (NEMB * DIM); e += nth) ws[WS_PART + e] = 0.f;
}

// Code-per-lane GEMM: lane owns one codebook column (registers), x broadcast
// from LDS. Block = 256 threads = 4 waves; block covers 64 rows (16/wave);
// each wave scans all 512 codes in 8 chunks of 64 (one code per lane).
__global__ __launch_bounds__(256, 4) void vq_main(
    const float* __restrict__ input, const float* __restrict__ embed,
    const float* __restrict__ ws, float* __restrict__ ws_part,
    float* __restrict__ out, int P) {
  __shared__ float xlds[64 * 64];   // [row][d] for this block's 64 rows
  __shared__ float pxx[256];
  __shared__ float xxs[64];         // per-row sum of squares

  const int tid  = threadIdx.x;
  const int lane = tid & 63;
  const int wid  = tid >> 6;                 // wave id 0..3
  const size_t rowBase = (size_t)blockIdx.x * 64;

  // ---- stage 64 rows of x into LDS (coalesced float4), xx partials ----
  {
    const float4* in4 = reinterpret_cast<const float4*>(input + rowBase * DIM);
    float4* x4 = reinterpret_cast<float4*>(xlds);
    float pp = 0.f;
#pragma unroll
    for (int k = 0; k < 4; ++k) {
      float4 v = in4[tid * 4 + k];
      x4[tid * 4 + k] = v;
      pp = fmaf(v.x, v.x, pp); pp = fmaf(v.y, v.y, pp);
      pp = fmaf(v.z, v.z, pp); pp = fmaf(v.w, v.w, pp);
    }
    pxx[tid] = pp;
  }
  __syncthreads();
  if (tid < 64)
    xxs[tid] = ((pxx[4 * tid] + pxx[4 * tid + 1]) + pxx[4 * tid + 2]) + pxx[4 * tid + 3];
  __syncthreads();

  // per-row running argmin state (local rows r = wid*16 + 0..15)
  float bD[16]; int bJ[16];
#pragma unroll
  for (int r = 0; r < 16; ++r) { bD[r] = 3.4e38f; bJ[r] = 0; }

#pragma unroll 1
  for (int c = 0; c < 8; ++c) {
    const int j = (c << 6) + lane;           // this lane's code for this chunk
    float en  = 0.f;
    float acc[16];
#pragma unroll
    for (int r = 0; r < 16; ++r) acc[r] = 0.f;

    // d in two halves so eR stays at 32 VGPRs
#pragma unroll
    for (int h = 0; h < 2; ++h) {
      float eR[32];
#pragma unroll
      for (int dd = 0; dd < 32; ++dd)
        eR[dd] = embed[(h * 32 + dd) * NEMB + j];   // coalesced, L2-hot
#pragma unroll
      for (int dd = 0; dd < 32; ++dd) en = fmaf(eR[dd], eR[dd], en);

#pragma unroll
      for (int rp = 0; rp < 8; ++rp) {
        const int ra = wid * 16 + rp * 2;
        const float4* xa = reinterpret_cast<const float4*>(xlds + ra * 64 + h * 32);
        const float4* xb = reinterpret_cast<const float4*>(xlds + (ra + 1) * 64 + h * 32);
        float aA = acc[2 * rp], aB = acc[2 * rp + 1];
#pragma unroll
        for (int dq = 0; dq < 8; ++dq) {
          float4 a = xa[dq], b = xb[dq];   // wave-uniform ds_read_b128 (broadcast)
          aA = fmaf(a.x, eR[4 * dq + 0], aA); aB = fmaf(b.x, eR[4 * dq + 0], aB);
          aA = fmaf(a.y, eR[4 * dq + 1], aA); aB = fmaf(b.y, eR[4 * dq + 1], aB);
          aA = fmaf(a.z, eR[4 * dq + 2], aA); aB = fmaf(b.z, eR[4 * dq + 2], aB);
          aA = fmaf(a.w, eR[4 * dq + 3], aA); aB = fmaf(b.w, eR[4 * dq + 3], aB);
        }
        acc[2 * rp] = aA; acc[2 * rp + 1] = aB;
      }
    }

    // distances + state update (strict < keeps first occurrence within lane)
#pragma unroll
    for (int rp = 0; rp < 8; ++rp) {
      const int ra = wid * 16 + rp * 2;
      float Da = (xxs[ra]     - 2.0f * acc[2 * rp])     + en;
      float Db = (xxs[ra + 1] - 2.0f * acc[2 * rp + 1]) + en;
      if (Da < bD[2 * rp])     { bD[2 * rp] = Da;     bJ[2 * rp] = j; }
      if (Db < bD[2 * rp + 1]) { bD[2 * rp + 1] = Db; bJ[2 * rp + 1] = j; }
    }
  }

  // ---- per-row cross-lane argmin (min dist, tie -> min index) + epilogue ----
  float* es = (P > 0) ? (ws_part + (size_t)(blockIdx.x % P) * (NEMB * DIM))
                      : (out + OUT_ES);
  float diffacc = 0.f;
#pragma unroll
  for (int r = 0; r < 16; ++r) {
    const int rl = wid * 16 + r;
    const size_t row = rowBase + rl;
    float D = bD[r]; int J = bJ[r];
#pragma unroll
    for (int s = 1; s < 64; s <<= 1) {
      float oD = __shfl_xor(D, s, 64);
      int   oJ = __shfl_xor(J, s, 64);
      if (oD < D || (oD == D && oJ < J)) { D = oD; J = oJ; }
    }
    // all lanes now hold the winning J; lane == d below
    float q  = ws[WS_ET + (size_t)J * DIM + lane];   // embedT row, coalesced
    float xv = xlds[rl * 64 + lane];
    out[OUT_Q + row * DIM + lane] = q;
    float er = q - xv;
    diffacc = fmaf(er, er, diffacc);
    atomicAdd(es + lane * NEMB + J, xv);             // embed_sum[d][j]
    if (lane == 0) {
      out[OUT_IND + row] = (float)J;
      atomicAdd(out + OUT_OH + J, 1.0f);
    }
  }
  // diff: wave butterfly + one atomic per wave
#pragma unroll
  for (int s = 1; s < 64; s <<= 1) diffacc += __shfl_xor(diffacc, s, 64);
  if (lane == 0)
    atomicAdd(out + OUT_DIFF, diffacc * (1.0f / (float)(NROWS * DIM)));
}

__global__ __launch_bounds__(256) void vq_reduce(const float* __restrict__ ws_part,
                                                 float* __restrict__ out, int P) {
  const int e = blockIdx.x * 256 + threadIdx.x;
  if (e < NEMB * DIM) {
    float s = 0.f;
    for (int p = 0; p < P; ++p) s += ws_part[(size_t)p * (NEMB * DIM) + e];
    out[OUT_ES + e] = s;
  }
}

extern "C" void kernel_launch(void* const* d_in, const int* in_sizes, int n_in,
                              void* d_out, int out_size, void* d_ws, size_t ws_size,
                              hipStream_t stream) {
  const float* input = (const float*)d_in[0];
  const float* embed = (const float*)d_in[1];
  float* out = (float*)d_out;
  float* ws  = (float*)d_ws;

  long ws_floats = (long)(ws_size / 4);
  long avail = ws_floats - WS_PART;
  int P = 0;
  if (avail > 0) {
    long p = avail / (NEMB * DIM);
    P = (int)(p > 32 ? 32 : p);
  }
  float* ws_part = ws + WS_PART;

  vq_prep<<<256, 256, 0, stream>>>(embed, ws, out, P);
  vq_main<<<NROWS / 64, 256, 0, stream>>>(input, embed, ws, ws_part, out, P);
  if (P > 0) vq_reduce<<<(NEMB * DIM + 255) / 256, 256, 0, stream>>>(ws_part, out, P);
}

// Round 4
// 715.269 us; speedup vs baseline: 7.9166x; 7.9166x over previous
//
#include <hip/hip_runtime.h>
#include <hip/hip_bf16.h>

// ---- problem geometry ----
#define NROWS   131072          // 32*4096
#define DIM     64
#define NEMB    512
// output offsets (floats)
#define OUT_Q     0
#define OUT_DIFF  8388608
#define OUT_IND   8388609
#define OUT_OH    8519681      // 8388609 + 131072
#define OUT_ES    8520193      // OUT_OH + 512
// ws layout (floats)
#define WS_EN     0
#define WS_ET     512           // embedT [512][64]
#define WS_KEY    33280         // u64 keys [131072] (2 floats each), 8B-aligned
#define WS_PART   295424        // P partial embed_sum copies
#define NCHUNK    4
#define CODES_PER_CHUNK 128

__global__ __launch_bounds__(256) void vq_prep(const float* __restrict__ embed,
                                               float* __restrict__ ws,
                                               float* __restrict__ out,
                                               int P, int doKey) {
  const int tid = blockIdx.x * 256 + threadIdx.x;
  const int nth = gridDim.x * 256;
  // embedT[j][d] = embed[d][j]
  for (int e = tid; e < NEMB * DIM; e += nth) {
    int j = e >> 6, d = e & 63;
    ws[WS_ET + e] = embed[d * NEMB + j];
  }
  // en[j] = sum_d embed[d][j]^2  (same op order as all passing rounds)
  for (int j = tid; j < NEMB; j += nth) {
    float s = 0.f;
    for (int d = 0; d < DIM; ++d) {
      float v = embed[d * NEMB + j];
      s = fmaf(v, v, s);
    }
    ws[WS_EN + j] = s;
  }
  // zero accumulator output regions (diff, onehot, embed_sum)
  if (tid == 0) out[OUT_DIFF] = 0.f;
  for (int e = tid; e < NEMB + NEMB * DIM; e += nth) out[OUT_OH + e] = 0.f;
  if (doKey) {
    unsigned long long* keys = reinterpret_cast<unsigned long long*>(ws + WS_KEY);
    for (int r = tid; r < NROWS; r += nth) keys[r] = ~0ULL;
  }
  for (long e = tid; e < (long)P * (NEMB * DIM); e += nth) ws[WS_PART + e] = 0.f;
}

// Distance + per-chunk argmin. One row per thread, 128 codes per chunk
// (blockIdx.y). Lean registers: x[64] + acc[8] ~= 95 VGPR -> ~5 waves/SIMD.
__global__ __launch_bounds__(256, 4) void vq_dist(
    const float* __restrict__ input, const float* __restrict__ embed,
    const float* __restrict__ ws, unsigned long long* __restrict__ keys) {
  const int i = blockIdx.x * 256 + threadIdx.x;     // row
  const int jbase = blockIdx.y * CODES_PER_CHUNK;   // wave-uniform

  float x[DIM];
  const float4* xin = reinterpret_cast<const float4*>(input + (size_t)i * DIM);
#pragma unroll
  for (int k = 0; k < 16; ++k) {
    float4 v = xin[k];
    x[4 * k + 0] = v.x; x[4 * k + 1] = v.y; x[4 * k + 2] = v.z; x[4 * k + 3] = v.w;
  }
  float xx = 0.f;
#pragma unroll
  for (int d = 0; d < DIM; ++d) xx = fmaf(x[d], x[d], xx);

  float best = 3.4e38f;
  int   bj   = jbase;
#pragma unroll 1
  for (int jt2 = 0; jt2 < CODES_PER_CHUNK; jt2 += 8) {
    const int jt = jbase + jt2;                     // wave-uniform
    float acc[8];
#pragma unroll
    for (int u = 0; u < 8; ++u) acc[u] = 0.f;
#pragma unroll
    for (int d = 0; d < DIM; ++d) {                 // d compile-time: x in VGPRs
      const float xv = x[d];
#pragma unroll
      for (int u = 0; u < 8; ++u)
        acc[u] = fmaf(xv, embed[d * NEMB + jt + u], acc[u]);  // uniform -> s_load
    }
#pragma unroll
    for (int u = 0; u < 8; ++u) {
      float dist = (xx - 2.0f * acc[u]) + ws[WS_EN + jt + u]; // np expr order
      if (dist < best) { best = dist; bj = jt + u; }          // first occurrence
    }
  }
  // lexicographic (D, J) min across chunks == global first-occurrence argmin
  const unsigned long long key =
      ((unsigned long long)__float_as_uint(fmaxf(best, 0.0f)) << 32) |
      (unsigned long long)(unsigned)bj;
  atomicMin(keys + i, key);
}

// Epilogue: block = 256 thr = 4 waves, 64 rows/block, lane == d.
__global__ __launch_bounds__(256) void vq_fin(
    const float* __restrict__ input, const float* __restrict__ ws,
    const unsigned long long* __restrict__ keys,
    float* __restrict__ ws_part, float* __restrict__ out, int P) {
  const int tid  = threadIdx.x;
  const int lane = tid & 63;
  const int wid  = tid >> 6;
  const size_t rowBase = (size_t)blockIdx.x * 64;

  float* es = (P > 0) ? (ws_part + (size_t)(blockIdx.x % P) * (NEMB * DIM))
                      : (out + OUT_ES);
  float diffacc = 0.f;
#pragma unroll 1
  for (int r = 0; r < 16; ++r) {
    const int rl = wid * 16 + r;
    const size_t row = rowBase + rl;
    const int J = (int)(keys[row] & 0xffffffffULL);   // uniform -> s_load
    float xv = input[row * DIM + lane];               // coalesced
    float q  = ws[WS_ET + (size_t)J * DIM + lane];    // embedT row, coalesced
    out[OUT_Q + row * DIM + lane] = q;
    float er = q - xv;
    diffacc = fmaf(er, er, diffacc);
    atomicAdd(es + lane * NEMB + J, xv);              // embed_sum[d][j]
    if (lane == 0) {
      out[OUT_IND + row] = (float)J;
      atomicAdd(out + OUT_OH + J, 1.0f);
    }
  }
#pragma unroll
  for (int s = 1; s < 64; s <<= 1) diffacc += __shfl_xor(diffacc, s, 64);
  if (lane == 0)
    atomicAdd(out + OUT_DIFF, diffacc * (1.0f / (float)(NROWS * DIM)));
}

__global__ __launch_bounds__(256) void vq_reduce(const float* __restrict__ ws_part,
                                                 float* __restrict__ out, int P) {
  const int e = blockIdx.x * 256 + threadIdx.x;
  if (e < NEMB * DIM) {
    float s = 0.f;
    for (int p = 0; p < P; ++p) s += ws_part[(size_t)p * (NEMB * DIM) + e];
    out[OUT_ES + e] = s;
  }
}

// Fallback (ws too small for keys): round-2 monolithic kernel, direct atomics.
__global__ __launch_bounds__(256) void vq_mono(
    const float* __restrict__ input, const float* __restrict__ embed,
    const float* __restrict__ ws, float* __restrict__ out) {
  const int i = blockIdx.x * 256 + threadIdx.x;
  float x[DIM];
  const float4* xin = reinterpret_cast<const float4*>(input + (size_t)i * DIM);
#pragma unroll
  for (int k = 0; k < 16; ++k) {
    float4 v = xin[k];
    x[4 * k + 0] = v.x; x[4 * k + 1] = v.y; x[4 * k + 2] = v.z; x[4 * k + 3] = v.w;
  }
  float xx = 0.f;
#pragma unroll
  for (int d = 0; d < DIM; ++d) xx = fmaf(x[d], x[d], xx);
  float best = 3.4e38f; int bj = 0;
#pragma unroll 1
  for (int jt = 0; jt < NEMB; jt += 8) {
    float acc[8];
#pragma unroll
    for (int u = 0; u < 8; ++u) acc[u] = 0.f;
#pragma unroll
    for (int d = 0; d < DIM; ++d) {
      const float xv = x[d];
#pragma unroll
      for (int u = 0; u < 8; ++u)
        acc[u] = fmaf(xv, embed[d * NEMB + jt + u], acc[u]);
    }
#pragma unroll
    for (int u = 0; u < 8; ++u) {
      float dist = (xx - 2.0f * acc[u]) + ws[WS_EN + jt + u];
      if (dist < best) { best = dist; bj = jt + u; }
    }
  }
  out[OUT_IND + i] = (float)bj;
  const float4* qr = reinterpret_cast<const float4*>(ws + WS_ET + (size_t)bj * DIM);
  float4* qo = reinterpret_cast<float4*>(out + (size_t)i * DIM);
  float dsum = 0.f;
#pragma unroll
  for (int k = 0; k < 16; ++k) {
    float4 q = qr[k];
    float e0 = q.x - x[4 * k + 0]; dsum = fmaf(e0, e0, dsum);
    float e1 = q.y - x[4 * k + 1]; dsum = fmaf(e1, e1, dsum);
    float e2 = q.z - x[4 * k + 2]; dsum = fmaf(e2, e2, dsum);
    float e3 = q.w - x[4 * k + 3]; dsum = fmaf(e3, e3, dsum);
    qo[k] = q;
  }
  __shared__ float red[256];
  red[threadIdx.x] = dsum;
  __syncthreads();
#pragma unroll
  for (int s = 128; s > 0; s >>= 1) {
    if (threadIdx.x < s) red[threadIdx.x] += red[threadIdx.x + s];
    __syncthreads();
  }
  if (threadIdx.x == 0)
    atomicAdd(out + OUT_DIFF, red[0] * (1.0f / (float)(NROWS * DIM)));
  atomicAdd(out + OUT_OH + bj, 1.0f);
#pragma unroll
  for (int d = 0; d < DIM; ++d) atomicAdd(out + OUT_ES + d * NEMB + bj, x[d]);
}

extern "C" void kernel_launch(void* const* d_in, const int* in_sizes, int n_in,
                              void* d_out, int out_size, void* d_ws, size_t ws_size,
                              hipStream_t stream) {
  const float* input = (const float*)d_in[0];
  const float* embed = (const float*)d_in[1];
  float* out = (float*)d_out;
  float* ws  = (float*)d_ws;

  long ws_floats = (long)(ws_size / 4);
  const bool big = ws_floats >= WS_PART;   // need 1.2 MB for keys path
  int P = 0;
  if (big) {
    long p = (ws_floats - WS_PART) / (NEMB * DIM);
    P = (int)(p > 32 ? 32 : p);
  }

  if (big) {
    unsigned long long* keys = reinterpret_cast<unsigned long long*>(ws + WS_KEY);
    float* ws_part = ws + WS_PART;
    vq_prep<<<256, 256, 0, stream>>>(embed, ws, out, P, 1);
    dim3 gdist(NROWS / 256, NCHUNK);
    vq_dist<<<gdist, 256, 0, stream>>>(input, embed, ws, keys);
    vq_fin<<<NROWS / 64, 256, 0, stream>>>(input, ws, keys, ws_part, out, P);
    if (P > 0) vq_reduce<<<(NEMB * DIM + 255) / 256, 256, 0, stream>>>(ws_part, out, P);
  } else {
    vq_prep<<<256, 256, 0, stream>>>(embed, ws, out, 0, 0);
    vq_mono<<<NROWS / 256, 256, 0, stream>>>(input, embed, ws, out);
  }
}